// Round 6
// baseline (130.903 us; speedup 1.0000x reference)
//
#include <hip/hip_runtime.h>

#define NN 262144   // nodes
#define DD 256      // channels
#define BB 1024     // graphs
#define GEPS 1e-5f

typedef float floatx4 __attribute__((ext_vector_type(4)));

// One block (512 threads = 8 waves) per graph -> 4 blocks/CU -> all 1024
// blocks co-resident (no scheduling rounds, per-CU imbalance averaged over
// 4 graphs). Self-contained: block finds its own [s0,s1) in the sorted batch
// via two-phase parallel lower_bound. Pass 1 streams the segment (HBM),
// pass 2 re-reads it (L3-hot) and writes out nontemporally (keeps x in L3).
__global__ __launch_bounds__(512) void k_main(const float4* __restrict__ x,
                                              const int* __restrict__ batch,
                                              const float4* __restrict__ w,
                                              const float4* __restrict__ bi,
                                              float4* __restrict__ out) {
    __shared__ int   s_coarse[2];
    __shared__ int   s_pos[2];     // each written >=once with the same value
    __shared__ float red_s[8];
    __shared__ float red_q[8];
    __shared__ float bc[2];

    const int b    = blockIdx.x;
    const int tid  = threadIdx.x;
    const int wid  = tid >> 6;     // 0..7
    const int lane = tid & 63;

    // --- phase 1: coarse lower_bound at stride 512 (targets b and b+1) ---
    if (tid < 2) s_coarse[tid] = NN;
    __syncthreads();
    {
        const int idx = tid << 9;              // 0,512,...,NN-512
        const int v   = batch[idx];
        if (v >= b)     atomicMin(&s_coarse[0], idx);
        if (v >= b + 1) atomicMin(&s_coarse[1], idx);
    }
    __syncthreads();
    // --- phase 2: exact boundary within (coarse-512, coarse] ---
    #pragma unroll
    for (int k = 0; k < 2; ++k) {
        const int tgt = b + k;
        const int cc  = s_coarse[k];
        const int i   = cc - 511 + tid;        // covers cc-511 .. cc
        if (i >= 0) {
            const int vi  = (i < NN) ? batch[i] : 0x7fffffff;
            const int vim = (i > 0) ? batch[i - 1] : (-2147483647 - 1);
            if (vi >= tgt && vim < tgt) s_pos[k] = i;   // unique hit
        }
    }
    __syncthreads();
    const int s0 = s_pos[0];
    const int s1 = s_pos[1];
    if (s1 <= s0) return;                      // empty graph (block-uniform)

    // --- pass 1: scalar sum / sumsq over the whole segment ---
    float s = 0.0f, q = 0.0f;
    for (int r = s0 + wid; r < s1; r += 8) {
        float4 v = x[r * 64 + lane];           // 64 lanes * 16B = one 1 KiB row
        s += v.x + v.y + v.z + v.w;
        q += v.x * v.x + v.y * v.y + v.z * v.z + v.w * v.w;
    }
    #pragma unroll
    for (int off = 32; off; off >>= 1) {
        s += __shfl_down(s, off, 64);
        q += __shfl_down(q, off, 64);
    }
    if (lane == 0) { red_s[wid] = s; red_q[wid] = q; }
    __syncthreads();
    if (tid == 0) {
        float ts = 0.0f, tq = 0.0f;
        #pragma unroll
        for (int i = 0; i < 8; ++i) { ts += red_s[i]; tq += red_q[i]; }
        const float norm = (float)(s1 - s0) * (float)DD;   // deg >= 1 here
        const float mean = ts / norm;
        const float var  = fmaxf(tq / norm - mean * mean, 0.0f);
        bc[0] = mean;
        bc[1] = 1.0f / (sqrtf(var) + GEPS);
    }
    __syncthreads();
    const float  mean = bc[0];
    const float  inv  = bc[1];
    const float4 wv   = w[lane];
    const float4 bv   = bi[lane];

    // --- pass 2: normalize; x re-read is L3-hot; out bypasses cache ---
    for (int r = s0 + wid; r < s1; r += 8) {
        float4 v = x[r * 64 + lane];
        floatx4 o;
        o.x = (v.x - mean) * inv * wv.x + bv.x;
        o.y = (v.y - mean) * inv * wv.y + bv.y;
        o.z = (v.z - mean) * inv * wv.z + bv.z;
        o.w = (v.w - mean) * inv * wv.w + bv.w;
        __builtin_nontemporal_store(o, (floatx4*)&out[r * 64 + lane]);
    }
}

extern "C" void kernel_launch(void* const* d_in, const int* in_sizes, int n_in,
                              void* d_out, int out_size, void* d_ws, size_t ws_size,
                              hipStream_t stream) {
    const float4* x     = (const float4*)d_in[0];
    const int*    batch = (const int*)d_in[1];
    const float4* w     = (const float4*)d_in[2];
    const float4* bi    = (const float4*)d_in[3];
    float4*       out   = (float4*)d_out;

    k_main<<<BB, 512, 0, stream>>>(x, batch, w, bi, out);
}